// Round 1
// baseline (256.920 us; speedup 1.0000x reference)
//
#include <hip/hip_runtime.h>

#define NB 16
#define NTQ 256
#define NTK 256
#define ND 256
#define NF 36
#define NH 8
#define NDK 32
#define NSF 6

// workspace layout (float offsets)
static const int QP_OFF = 0;                               // [B][H][TQ][DK]
static const int KP_OFF = NB*NH*NTQ*NDK;                   // [B][H][TK][DK]
static const int MV_OFF = KP_OFF + NB*NH*NTK*NDK;          // [B][TK][F] = mask*value
static const int HD_OFF = MV_OFF + NB*NTK*NF;              // [B][H][TQ][F] heads
// total = HD_OFF + NB*NH*NTQ*NF = 9,715,712 floats (~39 MB)

__device__ __forceinline__ float fast_tanh(float x){
    float e = __expf(2.0f*x);
    return 1.0f - 2.0f/(e + 1.0f);
}

// ---------------- kernel 1: mv = mask * value ----------------
__global__ void imta_mv(const float* __restrict__ mask, const float* __restrict__ value,
                        float* __restrict__ mv){
    int i = blockIdx.x*256 + threadIdx.x;
    mv[i] = mask[i]*value[i];
}

// ---------------- kernel 2: projections QP/KP ----------------
// QP[b][j][t][dk] = sum_d X[b][t][d] * W[j][d][dk]
__global__ void imta_proj(const float* __restrict__ query, const float* __restrict__ key_ts,
                          const float* __restrict__ Wq, const float* __restrict__ Wk,
                          float* __restrict__ ws){
    const int tile = blockIdx.x & 3, side = blockIdx.x >> 2;
    const int j = blockIdx.y, b = blockIdx.z;
    const int t0 = tile*64;
    const float* __restrict__ X = side ? key_ts : query;
    const float* __restrict__ W = side ? Wk : Wq;
    float* __restrict__ OUT = ws + (side ? KP_OFF : QP_OFF);
    __shared__ float xT[64][36];   // 64 rows x 32 d-chunk (pad 36: 16B-aligned float4)
    __shared__ float wT[32][36];   // 32 d x 32 dk
    const int tid = threadIdx.x;
    const int r  = tid >> 2, cp = (tid & 3)*8;    // x-chunk loads
    const int wr = tid >> 3, wc = (tid & 7)*4;    // w-chunk loads
    const int dk = tid & 31, tr = tid >> 5;       // compute mapping
    float acc[8] = {0.f,0.f,0.f,0.f,0.f,0.f,0.f,0.f};
    for (int dc = 0; dc < ND; dc += 32){
        float4 a0 = *(const float4*)(X + ((b*NTQ + t0 + r)*ND + dc + cp));
        float4 a1 = *(const float4*)(X + ((b*NTQ + t0 + r)*ND + dc + cp + 4));
        float4 w0 = *(const float4*)(W + (j*ND*NDK + (dc + wr)*NDK + wc));
        __syncthreads();
        *(float4*)&xT[r][cp]     = a0;
        *(float4*)&xT[r][cp + 4] = a1;
        *(float4*)&wT[wr][wc]    = w0;
        __syncthreads();
        #pragma unroll
        for (int kk = 0; kk < 32; ++kk){
            float wv = wT[kk][dk];                 // lanes consecutive dk: conflict-free
            #pragma unroll
            for (int i = 0; i < 8; ++i)
                acc[i] = fmaf(xT[tr + 8*i][kk], wv, acc[i]);  // broadcast read
        }
    }
    #pragma unroll
    for (int i = 0; i < 8; ++i)
        OUT[((b*NH + j)*NTQ + t0 + tr + 8*i)*NDK + dk] = acc[i];
}

// ---------------- kernel 3: attention per (b, head, 64-q tile) ----------------
// E[q][k] = exp(qp_row . kp_row)  (no row-max needed: ratio cancels, |score|<~25)
// head[q][f] = (sum_k E*m*v) / (sum_k E*m)
__global__ void __launch_bounds__(256, 2)
imta_attn(const float* __restrict__ mask, const float* __restrict__ value,
          float* __restrict__ ws){
    const int t0 = blockIdx.x*64;
    const int j = blockIdx.y, b = blockIdx.z;
    const float* __restrict__ QPbj = ws + QP_OFF + (b*NH + j)*NTQ*NDK;
    const float* __restrict__ KPbj = ws + KP_OFF + (b*NH + j)*NTK*NDK;
    const float* __restrict__ MVb  = ws + MV_OFF + b*NTK*NF;
    const float* __restrict__ Mb   = mask  + b*NTK*NF;
    const float* __restrict__ Vb   = value + b*NTK*NF;
    float* __restrict__ HDbj = ws + HD_OFF + (b*NH + j)*NTQ*NF;

    // single 65.8KB buffer: first kpT[32][258], then (after kv regs) E[64][257]
    __shared__ float smem[64*257];
    const int tid = threadIdx.x;

    {   // stage KP transposed: kpT[dk][k] = KP[k][dk]; stride 258 -> 2-way (free) writes
        const float4* __restrict__ src = (const float4*)KPbj;
        #pragma unroll
        for (int i = 0; i < 8; ++i){
            int fi = tid + i*256;
            float4 v = src[fi];
            int e0 = fi*4;
            int k = e0 >> 5, dk = e0 & 31;
            smem[(dk+0)*258 + k] = v.x;
            smem[(dk+1)*258 + k] = v.y;
            smem[(dk+2)*258 + k] = v.z;
            smem[(dk+3)*258 + k] = v.w;
        }
    }
    __syncthreads();
    float kv[32];                                  // this lane's full K-row (k = tid)
    #pragma unroll
    for (int d = 0; d < 32; ++d) kv[d] = smem[d*258 + tid];
    __syncthreads();                               // kpT dead; smem becomes E

    // phase 1: scores + exp; lane = k, loop q. QP reads are wave-uniform -> s_load.
    #pragma unroll 8
    for (int q = 0; q < 64; ++q){
        const float* __restrict__ qr = QPbj + (t0 + q)*NDK;
        float a0 = 0.f, a1 = 0.f, a2 = 0.f, a3 = 0.f;
        #pragma unroll
        for (int d = 0; d < 32; d += 4){
            a0 = fmaf(kv[d+0], qr[d+0], a0);
            a1 = fmaf(kv[d+1], qr[d+1], a1);
            a2 = fmaf(kv[d+2], qr[d+2], a2);
            a3 = fmaf(kv[d+3], qr[d+3], a3);
        }
        smem[q*257 + tid] = __expf((a0+a1)+(a2+a3));   // lanes consecutive: no conflict
    }
    __syncthreads();

    // phase 2: lane = q (64), wave w -> f-range [9w..9w+8]. mv/m reads wave-uniform -> s_load.
    const int q = tid & 63, w = tid >> 6, f0 = w*9;
    float num[9], den[9];
    #pragma unroll
    for (int i = 0; i < 9; ++i){ num[i] = 0.f; den[i] = 0.f; }
    for (int k = 0; k < 256; ++k){
        float e = smem[q*257 + k];                 // stride 257: (q+k)%32 -> conflict-free
        const float* __restrict__ mvr = MVb + k*NF + f0;
        const float* __restrict__ mr  = Mb  + k*NF + f0;
        #pragma unroll
        for (int i = 0; i < 9; ++i){
            num[i] = fmaf(e, mvr[i], num[i]);
            den[i] = fmaf(e, mr[i],  den[i]);
        }
    }
    float* __restrict__ Hd = HDbj + (t0 + q)*NF + f0;
    #pragma unroll
    for (int i = 0; i < 9; ++i){
        float n = num[i], d = den[i];
        if (d == 0.0f){                            // all-masked column: uniform softmax
            float s = 0.f;
            for (int k = 0; k < 256; ++k) s += Vb[k*NF + f0 + i];
            n = s; d = 256.0f;
        }
        Hd[i] = n/d;
    }
}

// ---------------- kernel 4: fused head-mix MLP ----------------
// out[b,q,d] = sum_s tanh( sum_f tanh(sum_h heads[b,q,f,h]*Wc[h,d] + bc[d]) * Wo1[f,s] + bo1[s] ) * Wo2[s] + bo2[d]
__global__ void imta_final(const float* __restrict__ Wc, const float* __restrict__ bc,
                           const float* __restrict__ Wo1, const float* __restrict__ bo1,
                           const float* __restrict__ Wo2, const float* __restrict__ bo2,
                           const float* __restrict__ ws, float* __restrict__ out){
    const int bq = blockIdx.x;
    const int b = bq >> 8, qq = bq & 255;
    const int tid = threadIdx.x;
    __shared__ float sh[NF*NH];     // sh[j*36+f] = heads for this (b,q)
    __shared__ float sW1[NF*NSF];   // Wo1[f][s]
    for (int t = tid; t < NF*NH; t += 256){
        int jj = t/NF, f = t - jj*NF;
        sh[t] = ws[HD_OFF + ((b*NH + jj)*NTQ + qq)*NF + f];
    }
    if (tid < NF*NSF) sW1[tid] = Wo1[tid];
    __syncthreads();
    const int d = tid;
    float wcr[8];
    #pragma unroll
    for (int h = 0; h < 8; ++h) wcr[h] = Wc[h*ND + d];
    const float bcd = bc[d];
    float a2[6];
    #pragma unroll
    for (int s = 0; s < 6; ++s) a2[s] = bo1[s];
    #pragma unroll
    for (int f4 = 0; f4 < NF; f4 += 4){
        float4 sv[8];
        #pragma unroll
        for (int h = 0; h < 8; ++h) sv[h] = *(const float4*)&sh[h*NF + f4];
        #pragma unroll
        for (int fi = 0; fi < 4; ++fi){
            float a = bcd;
            #pragma unroll
            for (int h = 0; h < 8; ++h)
                a = fmaf(reinterpret_cast<const float*>(&sv[h])[fi], wcr[h], a);
            float lf = fast_tanh(a);
            const int f = f4 + fi;
            #pragma unroll
            for (int s = 0; s < 6; ++s)
                a2[s] = fmaf(lf, sW1[f*NSF + s], a2[s]);
        }
    }
    float o = bo2[d];
    #pragma unroll
    for (int s = 0; s < 6; ++s)
        o = fmaf(fast_tanh(a2[s]), Wo2[s], o);
    out[(b*NTQ + qq)*ND + d] = o;
}

extern "C" void kernel_launch(void* const* d_in, const int* in_sizes, int n_in,
                              void* d_out, int out_size, void* d_ws, size_t ws_size,
                              hipStream_t stream){
    const float* query  = (const float*)d_in[0];
    const float* key_ts = (const float*)d_in[1];
    const float* value  = (const float*)d_in[2];
    const float* mask   = (const float*)d_in[3];
    const float* Wq     = (const float*)d_in[4];
    const float* Wk     = (const float*)d_in[5];
    const float* Wc     = (const float*)d_in[6];
    const float* bc     = (const float*)d_in[7];
    const float* Wo1    = (const float*)d_in[8];
    const float* bo1    = (const float*)d_in[9];
    const float* Wo2    = (const float*)d_in[10];
    const float* bo2    = (const float*)d_in[11];
    float* ws  = (float*)d_ws;
    float* out = (float*)d_out;
    (void)in_sizes; (void)n_in; (void)out_size; (void)ws_size;

    imta_mv  <<<dim3(NB*NTK*NF/256), dim3(256), 0, stream>>>(mask, value, ws + MV_OFF);
    imta_proj<<<dim3(8, NH, NB),     dim3(256), 0, stream>>>(query, key_ts, Wq, Wk, ws);
    imta_attn<<<dim3(4, NH, NB),     dim3(256), 0, stream>>>(mask, value, ws);
    imta_final<<<dim3(NB*NTQ),       dim3(256), 0, stream>>>(Wc, bc, Wo1, bo1, Wo2, bo2, ws, out);
}

// Round 2
// 227.234 us; speedup vs baseline: 1.1306x; 1.1306x over previous
//
#include <hip/hip_runtime.h>

#define NB 16
#define NTQ 256
#define NTK 256
#define ND 256
#define NF 36
#define NH 8
#define NDK 32
#define NSF 6

// workspace layout (float offsets)
static const int QP_OFF  = 0;                               // [B][H][TQ][DK]
static const int KP_OFF  = NB*NH*NTQ*NDK;                   // [B][H][TK][DK]
static const int MVM_OFF = KP_OFF + NB*NH*NTK*NDK;          // [B][4][TK][20]  (9 mv | 9 m | 2 pad)
static const int HD_OFF  = MVM_OFF + NB*4*NTK*20;           // [B][H][TQ][F] heads
// total = HD_OFF + NB*NH*NTQ*NF ≈ 3.6M floats (~14.4 MB)

__device__ __forceinline__ float fast_tanh(float x){
    float e = __expf(2.0f*x);
    return 1.0f - 2.0f/(e + 1.0f);
}

// ---------------- kernel 1: pack mvm[b][g][k][20] = {mask*value, mask} for f=9g..9g+8 ----------------
__global__ void imta_mvm(const float* __restrict__ mask, const float* __restrict__ value,
                         float* __restrict__ mvm){
    const int row = blockIdx.x*256 + threadIdx.x;      // 16*4*256 rows
    const int b = row >> 10, g = (row >> 8) & 3, k = row & 255;
    const float* __restrict__ m = mask  + (b*NTK + k)*NF + 9*g;
    const float* __restrict__ v = value + (b*NTK + k)*NF + 9*g;
    float* __restrict__ r = mvm + row*20;
    #pragma unroll
    for (int i = 0; i < 9; ++i){
        float mi = m[i];
        r[i]     = mi * v[i];
        r[9 + i] = mi;
    }
}

// ---------------- kernel 2: projections QP/KP ----------------
__global__ void imta_proj(const float* __restrict__ query, const float* __restrict__ key_ts,
                          const float* __restrict__ Wq, const float* __restrict__ Wk,
                          float* __restrict__ ws){
    const int tile = blockIdx.x & 3, side = blockIdx.x >> 2;
    const int j = blockIdx.y, b = blockIdx.z;
    const int t0 = tile*64;
    const float* __restrict__ X = side ? key_ts : query;
    const float* __restrict__ W = side ? Wk : Wq;
    float* __restrict__ OUT = ws + (side ? KP_OFF : QP_OFF);
    __shared__ float xT[64][36];
    __shared__ float wT[32][36];
    const int tid = threadIdx.x;
    const int r  = tid >> 2, cp = (tid & 3)*8;
    const int wr = tid >> 3, wc = (tid & 7)*4;
    const int dk = tid & 31, tr = tid >> 5;
    float acc[8] = {0.f,0.f,0.f,0.f,0.f,0.f,0.f,0.f};
    for (int dc = 0; dc < ND; dc += 32){
        float4 a0 = *(const float4*)(X + ((b*NTQ + t0 + r)*ND + dc + cp));
        float4 a1 = *(const float4*)(X + ((b*NTQ + t0 + r)*ND + dc + cp + 4));
        float4 w0 = *(const float4*)(W + (j*ND*NDK + (dc + wr)*NDK + wc));
        __syncthreads();
        *(float4*)&xT[r][cp]     = a0;
        *(float4*)&xT[r][cp + 4] = a1;
        *(float4*)&wT[wr][wc]    = w0;
        __syncthreads();
        #pragma unroll
        for (int kk = 0; kk < 32; ++kk){
            float wv = wT[kk][dk];
            #pragma unroll
            for (int i = 0; i < 8; ++i)
                acc[i] = fmaf(xT[tr + 8*i][kk], wv, acc[i]);
        }
    }
    #pragma unroll
    for (int i = 0; i < 8; ++i)
        OUT[((b*NH + j)*NTQ + t0 + tr + 8*i)*NDK + dk] = acc[i];
}

// ---------------- kernel 3: attention per (b, head, 64-q tile) ----------------
__global__ void __launch_bounds__(256, 2)
imta_attn(const float* __restrict__ qp, const float* __restrict__ kp,
          const float* __restrict__ mvm, const float* __restrict__ value,
          float* __restrict__ hd){
    const int t0 = blockIdx.x*64;
    const int j = blockIdx.y, b = blockIdx.z;
    const float* __restrict__ QPbj = qp + (b*NH + j)*NTQ*NDK;
    const float* __restrict__ KPbj = kp + (b*NH + j)*NTK*NDK;
    const float* __restrict__ Vb   = value + b*NTK*NF;
    float* __restrict__ HDbj = hd + (b*NH + j)*NTQ*NF;

    __shared__ float smem[64*257];
    const int tid = threadIdx.x;

    {   // stage KP transposed: kpT[dk][k], stride 258 -> 2-way (free) write aliasing
        const float4* __restrict__ src = (const float4*)KPbj;
        #pragma unroll
        for (int i = 0; i < 8; ++i){
            int fi = tid + i*256;
            float4 v = src[fi];
            int e0 = fi*4;
            int k = e0 >> 5, dk = e0 & 31;
            smem[(dk+0)*258 + k] = v.x;
            smem[(dk+1)*258 + k] = v.y;
            smem[(dk+2)*258 + k] = v.z;
            smem[(dk+3)*258 + k] = v.w;
        }
    }
    __syncthreads();
    float kv[32];                                  // this lane's full K-row (k = tid)
    #pragma unroll
    for (int d = 0; d < 32; ++d) kv[d] = smem[d*258 + tid];
    __syncthreads();                               // kpT dead; smem becomes E

    // phase 1: scores + exp; lane = k, loop q. QP reads wave-uniform -> s_load.
    #pragma unroll 8
    for (int q = 0; q < 64; ++q){
        const float* __restrict__ qr = QPbj + (t0 + q)*NDK;
        float a0 = 0.f, a1 = 0.f, a2 = 0.f, a3 = 0.f;
        #pragma unroll
        for (int d = 0; d < 32; d += 4){
            a0 = fmaf(kv[d+0], qr[d+0], a0);
            a1 = fmaf(kv[d+1], qr[d+1], a1);
            a2 = fmaf(kv[d+2], qr[d+2], a2);
            a3 = fmaf(kv[d+3], qr[d+3], a3);
        }
        smem[q*257 + tid] = __expf((a0+a1)+(a2+a3));
    }
    __syncthreads();

    // phase 2: lane = q (64), wave w -> f-range [9w..9w+8].
    const int q = tid & 63;
    int g = __builtin_amdgcn_readfirstlane(tid >> 6);      // provably wave-uniform fgroup
    const float* __restrict__ R = mvm + (b*4 + g)*NTK*20;  // packed rows: 9 mv | 9 m | pad
    float num[9], den[9];
    #pragma unroll
    for (int i = 0; i < 9; ++i){ num[i] = 0.f; den[i] = 0.f; }
    #pragma unroll 4
    for (int k = 0; k < 256; ++k){
        float e = smem[q*257 + k];                 // bank (q+k)%32 -> conflict-free
        const float* __restrict__ rk = R + k*20;
        float4 c0 = *(const float4*)(rk);
        float4 c1 = *(const float4*)(rk + 4);
        float4 c2 = *(const float4*)(rk + 8);
        float4 c3 = *(const float4*)(rk + 12);
        float2 c4 = *(const float2*)(rk + 16);
        num[0]=fmaf(e,c0.x,num[0]); num[1]=fmaf(e,c0.y,num[1]); num[2]=fmaf(e,c0.z,num[2]); num[3]=fmaf(e,c0.w,num[3]);
        num[4]=fmaf(e,c1.x,num[4]); num[5]=fmaf(e,c1.y,num[5]); num[6]=fmaf(e,c1.z,num[6]); num[7]=fmaf(e,c1.w,num[7]);
        num[8]=fmaf(e,c2.x,num[8]);
        den[0]=fmaf(e,c2.y,den[0]); den[1]=fmaf(e,c2.z,den[1]); den[2]=fmaf(e,c2.w,den[2]);
        den[3]=fmaf(e,c3.x,den[3]); den[4]=fmaf(e,c3.y,den[4]); den[5]=fmaf(e,c3.z,den[5]); den[6]=fmaf(e,c3.w,den[6]);
        den[7]=fmaf(e,c4.x,den[7]); den[8]=fmaf(e,c4.y,den[8]);
    }
    const int f0 = g*9;
    float* __restrict__ Hd = HDbj + (t0 + q)*NF + f0;
    #pragma unroll
    for (int i = 0; i < 9; ++i){
        float n = num[i], d = den[i];
        if (d == 0.0f){                            // all-masked column: uniform softmax
            float s = 0.f;
            for (int k = 0; k < 256; ++k) s += Vb[k*NF + f0 + i];
            n = s; d = 256.0f;
        }
        Hd[i] = n/d;
    }
}

// ---------------- kernel 4: fused head-mix MLP ----------------
__global__ void imta_final(const float* __restrict__ Wc, const float* __restrict__ bc,
                           const float* __restrict__ Wo1, const float* __restrict__ bo1,
                           const float* __restrict__ Wo2, const float* __restrict__ bo2,
                           const float* __restrict__ ws, float* __restrict__ out){
    const int bq = blockIdx.x;
    const int b = bq >> 8, qq = bq & 255;
    const int tid = threadIdx.x;
    __shared__ float sh[NF*NH];
    __shared__ float sW1[NF*NSF];
    for (int t = tid; t < NF*NH; t += 256){
        int jj = t/NF, f = t - jj*NF;
        sh[t] = ws[HD_OFF + ((b*NH + jj)*NTQ + qq)*NF + f];
    }
    if (tid < NF*NSF) sW1[tid] = Wo1[tid];
    __syncthreads();
    const int d = tid;
    float wcr[8];
    #pragma unroll
    for (int h = 0; h < 8; ++h) wcr[h] = Wc[h*ND + d];
    const float bcd = bc[d];
    float a2[6];
    #pragma unroll
    for (int s = 0; s < 6; ++s) a2[s] = bo1[s];
    #pragma unroll
    for (int f4 = 0; f4 < NF; f4 += 4){
        float4 sv[8];
        #pragma unroll
        for (int h = 0; h < 8; ++h) sv[h] = *(const float4*)&sh[h*NF + f4];
        #pragma unroll
        for (int fi = 0; fi < 4; ++fi){
            float a = bcd;
            #pragma unroll
            for (int h = 0; h < 8; ++h)
                a = fmaf(reinterpret_cast<const float*>(&sv[h])[fi], wcr[h], a);
            float lf = fast_tanh(a);
            const int f = f4 + fi;
            #pragma unroll
            for (int s = 0; s < 6; ++s)
                a2[s] = fmaf(lf, sW1[f*NSF + s], a2[s]);
        }
    }
    float o = bo2[d];
    #pragma unroll
    for (int s = 0; s < 6; ++s)
        o = fmaf(fast_tanh(a2[s]), Wo2[s], o);
    out[(b*NTQ + qq)*ND + d] = o;
}

extern "C" void kernel_launch(void* const* d_in, const int* in_sizes, int n_in,
                              void* d_out, int out_size, void* d_ws, size_t ws_size,
                              hipStream_t stream){
    const float* query  = (const float*)d_in[0];
    const float* key_ts = (const float*)d_in[1];
    const float* value  = (const float*)d_in[2];
    const float* mask   = (const float*)d_in[3];
    const float* Wq     = (const float*)d_in[4];
    const float* Wk     = (const float*)d_in[5];
    const float* Wc     = (const float*)d_in[6];
    const float* bc     = (const float*)d_in[7];
    const float* Wo1    = (const float*)d_in[8];
    const float* bo1    = (const float*)d_in[9];
    const float* Wo2    = (const float*)d_in[10];
    const float* bo2    = (const float*)d_in[11];
    float* ws  = (float*)d_ws;
    float* out = (float*)d_out;
    (void)in_sizes; (void)n_in; (void)out_size; (void)ws_size;

    imta_mvm <<<dim3(NB*4*NTK/256), dim3(256), 0, stream>>>(mask, value, ws + MVM_OFF);
    imta_proj<<<dim3(8, NH, NB),    dim3(256), 0, stream>>>(query, key_ts, Wq, Wk, ws);
    imta_attn<<<dim3(4, NH, NB),    dim3(256), 0, stream>>>(ws + QP_OFF, ws + KP_OFF,
                                                            ws + MVM_OFF, value, ws + HD_OFF);
    imta_final<<<dim3(NB*NTQ),      dim3(256), 0, stream>>>(Wc, bc, Wo1, bo1, Wo2, bo2, ws, out);
}

// Round 3
// 154.824 us; speedup vs baseline: 1.6594x; 1.4677x over previous
//
#include <hip/hip_runtime.h>

#define NB 16
#define NTQ 256
#define NTK 256
#define ND 256
#define NF 36
#define NH 8
#define NDK 32
#define NSF 6

typedef __attribute__((ext_vector_type(8))) short short8;
typedef __attribute__((ext_vector_type(4))) float f32x4;
#define MFMA16(a,b,c) __builtin_amdgcn_mfma_f32_16x16x32_bf16(a,b,c,0,0,0)

// ---- workspace byte offsets (all 256B aligned) ----
#define SZ_X   (16*256*256*2)            // one bf16 image of query/key
#define XQH_OFF 0
#define XQL_OFF (XQH_OFF + SZ_X)
#define XKH_OFF (XQL_OFF + SZ_X)
#define XKL_OFF (XKH_OFF + SZ_X)
#define SZ_WT  (2*256*256*2)
#define WTH_OFF (XKL_OFF + SZ_X)
#define WTL_OFF (WTH_OFF + SZ_WT)
#define SZ_QP  (16*8*256*32*2)
#define QPH_OFF (WTL_OFF + SZ_WT)
#define QPL_OFF (QPH_OFF + SZ_QP)
#define KPH_OFF (QPL_OFF + SZ_QP)
#define KPL_OFF (KPH_OFF + SZ_QP)
#define SZ_RT  (16*80*256*2)
#define RT_OFF  (KPL_OFF + SZ_QP)
#define HD_OFF  (RT_OFF + SZ_RT)         // fp32 [16][8][256][36]
// end = HD_OFF + 4718592 ≈ 22.7 MB

__device__ __forceinline__ short f2bf(float x){
    union { float f; unsigned u; } v; v.f = x;
    unsigned r = v.u + 0x7fffu + ((v.u >> 16) & 1u);
    return (short)(r >> 16);
}
__device__ __forceinline__ float bf2f(short s){
    union { float f; unsigned u; } v; v.u = ((unsigned)(unsigned short)s) << 16;
    return v.f;
}
__device__ __forceinline__ float fast_tanh(float x){
    float e = __expf(2.0f*x);
    return 1.0f - 2.0f/(e + 1.0f);
}
__device__ __forceinline__ short8 ld8(const short* p){ return *(const short8*)p; }

// ---------------- pack query/key into bf16 hi/lo ----------------
__global__ void imta_pack_x(const float* __restrict__ query, const float* __restrict__ key_ts,
                            char* __restrict__ wsb){
    int i = blockIdx.x*256 + threadIdx.x;      // 1,048,576 elems
    short* qh = (short*)(wsb + XQH_OFF); short* ql = (short*)(wsb + XQL_OFF);
    short* kh = (short*)(wsb + XKH_OFF); short* kl = (short*)(wsb + XKL_OFF);
    float q = query[i];
    short h = f2bf(q); qh[i] = h; ql[i] = f2bf(q - bf2f(h));
    float k = key_ts[i];
    short h2 = f2bf(k); kh[i] = h2; kl[i] = f2bf(k - bf2f(h2));
}

// ---------------- pack W into WT[side][j*32+dk][d] bf16 hi/lo ----------------
__global__ void imta_pack_w(const float* __restrict__ Wq, const float* __restrict__ Wk,
                            char* __restrict__ wsb){
    int idx = blockIdx.x*256 + threadIdx.x;    // 131072
    int side = idx >> 16, rem = idx & 65535;
    int n = rem >> 8, d = rem & 255;
    int j = n >> 5, dk = n & 31;
    float w = (side ? Wk : Wq)[(j*ND + d)*NDK + dk];
    short* wh = (short*)(wsb + WTH_OFF) + side*65536;
    short* wl = (short*)(wsb + WTL_OFF) + side*65536;
    short h = f2bf(w);
    wh[n*256 + d] = h; wl[n*256 + d] = f2bf(w - bf2f(h));
}

// ---------------- pack RT[b][f'][k]: f'=2f -> bf16(m*v), f'=2f+1 -> bf16(m) ----------------
__global__ void imta_pack_rt(const float* __restrict__ mask, const float* __restrict__ value,
                             char* __restrict__ wsb){
    int f = blockIdx.x, b = blockIdx.y, k = threadIdx.x;  // f in [0,40)
    short* rt = (short*)(wsb + RT_OFF) + b*80*256;
    if (f < NF){
        float m = mask [(b*NTK + k)*NF + f];
        float v = value[(b*NTK + k)*NF + f];
        rt[(2*f    )*256 + k] = f2bf(m*v);
        rt[(2*f + 1)*256 + k] = f2bf(m);
    } else {
        rt[(2*f    )*256 + k] = 0;
        rt[(2*f + 1)*256 + k] = 0;
    }
}

// ---------------- proj via MFMA: QP/KP = X @ Wstack, hi/lo 3-pass ----------------
// block: (mt,nhalf | side | b); out 64 rows x 128 cols of [t][(j,dk)]
__global__ void imta_proj(char* __restrict__ wsb){
    const int mt = blockIdx.x >> 1, nh = blockIdx.x & 1;
    const int side = blockIdx.y, b = blockIdx.z;
    const int tid = threadIdx.x, w = tid >> 6, lane = tid & 63;
    const int col = lane & 15, quad = lane >> 4;
    const int t0 = mt*64;
    const short* XH = (const short*)(wsb + (side ? XKH_OFF : XQH_OFF)) + b*NTQ*ND;
    const short* XL = (const short*)(wsb + (side ? XKL_OFF : XQL_OFF)) + b*NTQ*ND;
    const short* WH = (const short*)(wsb + WTH_OFF) + side*65536;
    const short* WL = (const short*)(wsb + WTL_OFF) + side*65536;
    f32x4 acc[4][2];
    #pragma unroll
    for (int m = 0; m < 4; ++m){ acc[m][0] = (f32x4)0.f; acc[m][1] = (f32x4)0.f; }
    for (int kb = 0; kb < 8; ++kb){
        const int ko = kb*32 + quad*8;
        short8 ah[4], al[4], bh[2], bl[2];
        #pragma unroll
        for (int m = 0; m < 4; ++m){
            const int t = t0 + m*16 + col;
            ah[m] = ld8(XH + t*ND + ko);
            al[m] = ld8(XL + t*ND + ko);
        }
        #pragma unroll
        for (int nt = 0; nt < 2; ++nt){
            const int n = (nh*8 + w*2 + nt)*16 + col;
            bh[nt] = ld8(WH + n*256 + ko);
            bl[nt] = ld8(WL + n*256 + ko);
        }
        #pragma unroll
        for (int m = 0; m < 4; ++m)
            #pragma unroll
            for (int nt = 0; nt < 2; ++nt){
                acc[m][nt] = MFMA16(al[m], bh[nt], acc[m][nt]);
                acc[m][nt] = MFMA16(ah[m], bl[nt], acc[m][nt]);
                acc[m][nt] = MFMA16(ah[m], bh[nt], acc[m][nt]);
            }
    }
    short* oh = (short*)(wsb + (side ? KPH_OFF : QPH_OFF));
    short* ol = (short*)(wsb + (side ? KPL_OFF : QPL_OFF));
    #pragma unroll
    for (int m = 0; m < 4; ++m)
        #pragma unroll
        for (int nt = 0; nt < 2; ++nt){
            const int n = (nh*8 + w*2 + nt)*16 + col;
            const int j = n >> 5, dk = n & 31;
            #pragma unroll
            for (int r = 0; r < 4; ++r){
                const int t = t0 + m*16 + quad*4 + r;
                float v = acc[m][nt][r];
                short h = f2bf(v);
                size_t o = (size_t)(((b*NH + j)*NTQ + t)*NDK + dk);
                oh[o] = h; ol[o] = f2bf(v - bf2f(h));
            }
        }
}

// ---------------- attention via MFMA ----------------
// block: (qtile | j | b). phase1: scores (hi/lo 3-pass) -> exp -> E(bf16) in LDS
// phase2: E @ RT^T (interleaved mv/m cols) -> shfl div -> heads
__global__ void imta_attn(char* __restrict__ wsb, const float* __restrict__ value){
    const int t0 = blockIdx.x*64;
    const int j = blockIdx.y, b = blockIdx.z;
    const int tid = threadIdx.x, w = tid >> 6, lane = tid & 63;
    const int col = lane & 15, quad = lane >> 4;
    __shared__ short sE[64*264];               // 33.8 KB; later overlaid by sH
    const short* QH = (const short*)(wsb + QPH_OFF) + (b*NH + j)*NTQ*NDK;
    const short* QL = (const short*)(wsb + QPL_OFF) + (b*NH + j)*NTQ*NDK;
    const short* KH = (const short*)(wsb + KPH_OFF) + (b*NH + j)*NTK*NDK;
    const short* KL = (const short*)(wsb + KPL_OFF) + (b*NH + j)*NTK*NDK;
    const short* RT = (const short*)(wsb + RT_OFF) + b*80*256;
    float* HD = (float*)(wsb + HD_OFF) + (b*NH + j)*NTQ*NF;

    // phase 1: wave w covers keys [64w, 64w+64)
    short8 ah[4], al[4];
    #pragma unroll
    for (int m = 0; m < 4; ++m){
        const int t = t0 + m*16 + col;
        ah[m] = ld8(QH + t*NDK + quad*8);
        al[m] = ld8(QL + t*NDK + quad*8);
    }
    #pragma unroll
    for (int nt = 0; nt < 4; ++nt){
        const int key0 = w*64 + nt*16;
        short8 bh = ld8(KH + (key0 + col)*NDK + quad*8);
        short8 bl = ld8(KL + (key0 + col)*NDK + quad*8);
        f32x4 acc[4];
        #pragma unroll
        for (int m = 0; m < 4; ++m){
            f32x4 c = (f32x4)0.f;
            c = MFMA16(al[m], bh, c);
            c = MFMA16(ah[m], bl, c);
            c = MFMA16(ah[m], bh, c);
            acc[m] = c;
        }
        const int key = key0 + col;
        #pragma unroll
        for (int m = 0; m < 4; ++m)
            #pragma unroll
            for (int r = 0; r < 4; ++r){
                const int q = m*16 + quad*4 + r;
                sE[q*264 + key] = f2bf(__expf(acc[m][r]));
            }
    }
    __syncthreads();

    // phase 2: wave w owns q-range [16w, 16w+16)
    const int q0 = w*16;
    f32x4 acc2[5];
    #pragma unroll
    for (int nt = 0; nt < 5; ++nt) acc2[nt] = (f32x4)0.f;
    #pragma unroll 2
    for (int kb = 0; kb < 8; ++kb){
        const int ko = kb*32 + quad*8;
        short8 a = *(const short8*)&sE[(q0 + col)*264 + ko];
        #pragma unroll
        for (int nt = 0; nt < 5; ++nt){
            short8 bb = ld8(RT + (nt*16 + col)*256 + ko);
            acc2[nt] = MFMA16(a, bb, acc2[nt]);
        }
    }
    __syncthreads();                           // all phase-2 sE reads done
    float* sH = (float*)sE;                    // [64][40] heads staging
    #pragma unroll
    for (int nt = 0; nt < 5; ++nt)
        #pragma unroll
        for (int r = 0; r < 4; ++r){
            float v = acc2[nt][r];
            float o = __shfl_xor(v, 1, 64);
            if (!(col & 1)){
                const int f = nt*8 + (col >> 1);
                if (f < NF){
                    float num = v, den = o, h;
                    if (den != 0.0f) h = num/den;
                    else {
                        float s = 0.f;
                        for (int k = 0; k < NTK; ++k) s += value[(b*NTK + k)*NF + f];
                        h = s * (1.0f/256.0f);
                    }
                    sH[(q0 + quad*4 + r)*40 + f] = h;
                }
            }
        }
    __syncthreads();
    for (int idx = tid; idx < 64*NF; idx += 256){
        const int q = idx/NF, f = idx - q*NF;
        HD[(t0 + q)*NF + f] = sH[q*40 + f];
    }
}

// ---------------- fused head-mix MLP ----------------
__global__ void imta_final(const float* __restrict__ Wc, const float* __restrict__ bc,
                           const float* __restrict__ Wo1, const float* __restrict__ bo1,
                           const float* __restrict__ Wo2, const float* __restrict__ bo2,
                           const float* __restrict__ hd, float* __restrict__ out){
    const int bq = blockIdx.x;
    const int b = bq >> 8, qq = bq & 255;
    const int tid = threadIdx.x;
    __shared__ float sh[NF*NH];
    __shared__ float sW1[NF*NSF];
    for (int t = tid; t < NF*NH; t += 256){
        int jj = t/NF, f = t - jj*NF;
        sh[t] = hd[((b*NH + jj)*NTQ + qq)*NF + f];
    }
    if (tid < NF*NSF) sW1[tid] = Wo1[tid];
    __syncthreads();
    const int d = tid;
    float wcr[8];
    #pragma unroll
    for (int h = 0; h < 8; ++h) wcr[h] = Wc[h*ND + d];
    const float bcd = bc[d];
    float a2[6];
    #pragma unroll
    for (int s = 0; s < 6; ++s) a2[s] = bo1[s];
    #pragma unroll
    for (int f4 = 0; f4 < NF; f4 += 4){
        float4 sv[8];
        #pragma unroll
        for (int h = 0; h < 8; ++h) sv[h] = *(const float4*)&sh[h*NF + f4];
        #pragma unroll
        for (int fi = 0; fi < 4; ++fi){
            float a = bcd;
            #pragma unroll
            for (int h = 0; h < 8; ++h)
                a = fmaf(reinterpret_cast<const float*>(&sv[h])[fi], wcr[h], a);
            float lf = fast_tanh(a);
            const int f = f4 + fi;
            #pragma unroll
            for (int s = 0; s < 6; ++s)
                a2[s] = fmaf(lf, sW1[f*NSF + s], a2[s]);
        }
    }
    float o = bo2[d];
    #pragma unroll
    for (int s = 0; s < 6; ++s)
        o = fmaf(fast_tanh(a2[s]), Wo2[s], o);
    out[(b*NTQ + qq)*ND + d] = o;
}

extern "C" void kernel_launch(void* const* d_in, const int* in_sizes, int n_in,
                              void* d_out, int out_size, void* d_ws, size_t ws_size,
                              hipStream_t stream){
    const float* query  = (const float*)d_in[0];
    const float* key_ts = (const float*)d_in[1];
    const float* value  = (const float*)d_in[2];
    const float* mask   = (const float*)d_in[3];
    const float* Wq     = (const float*)d_in[4];
    const float* Wk     = (const float*)d_in[5];
    const float* Wc     = (const float*)d_in[6];
    const float* bc     = (const float*)d_in[7];
    const float* Wo1    = (const float*)d_in[8];
    const float* bo1    = (const float*)d_in[9];
    const float* Wo2    = (const float*)d_in[10];
    const float* bo2    = (const float*)d_in[11];
    char* wsb  = (char*)d_ws;
    float* out = (float*)d_out;
    (void)in_sizes; (void)n_in; (void)out_size; (void)ws_size;

    imta_pack_x <<<dim3(4096),     dim3(256), 0, stream>>>(query, key_ts, wsb);
    imta_pack_w <<<dim3(512),      dim3(256), 0, stream>>>(Wq, Wk, wsb);
    imta_pack_rt<<<dim3(40, 16),   dim3(256), 0, stream>>>(mask, value, wsb);
    imta_proj   <<<dim3(8, 2, 16), dim3(256), 0, stream>>>(wsb);
    imta_attn   <<<dim3(4, 8, 16), dim3(256), 0, stream>>>(wsb, value);
    imta_final  <<<dim3(4096),     dim3(256), 0, stream>>>(Wc, bc, Wo1, bo1, Wo2, bo2,
                                                           (const float*)(wsb + HD_OFF), out);
}

// Round 4
// 142.409 us; speedup vs baseline: 1.8041x; 1.0872x over previous
//
#include <hip/hip_runtime.h>

#define NB 16
#define NTQ 256
#define NTK 256
#define ND 256
#define NF 36
#define NH 8
#define NDK 32
#define NSF 6

typedef __attribute__((ext_vector_type(8))) short short8;
typedef __attribute__((ext_vector_type(4))) float f32x4;
#define MFMA16(a,b,c) __builtin_amdgcn_mfma_f32_16x16x32_bf16(a,b,c,0,0,0)

// ---- workspace byte offsets ----
#define SZ_QP  (16*8*256*32*2)
#define QPH_OFF 0
#define QPL_OFF (QPH_OFF + SZ_QP)
#define KPH_OFF (QPL_OFF + SZ_QP)
#define KPL_OFF (KPH_OFF + SZ_QP)
#define SZ_RT  (16*80*256*2)
#define RT_OFF  (KPL_OFF + SZ_QP)
#define HD_OFF  (RT_OFF + SZ_RT)         // fp32 [16][8][256][36]
// total ~21.5 MB

__device__ __forceinline__ short f2bf(float x){
    union { float f; unsigned u; } v; v.f = x;
    unsigned r = v.u + 0x7fffu + ((v.u >> 16) & 1u);
    return (short)(r >> 16);
}
__device__ __forceinline__ float bf2f(short s){
    union { float f; unsigned u; } v; v.u = ((unsigned)(unsigned short)s) << 16;
    return v.f;
}
__device__ __forceinline__ float fast_tanh(float x){
    float e = __expf(2.0f*x);
    return 1.0f - 2.0f/(e + 1.0f);
}
__device__ __forceinline__ short8 ld8(const short* p){ return *(const short8*)p; }

// hi/lo bf16 split of 8 consecutive floats (RNE hi, RNE residual lo)
__device__ __forceinline__ void cvt8(const float* __restrict__ p, short8& h8, short8& l8){
    f32x4 a = *(const f32x4*)p;
    f32x4 c = *(const f32x4*)(p + 4);
    #pragma unroll
    for (int i = 0; i < 4; ++i){
        short h0 = f2bf(a[i]); h8[i]   = h0; l8[i]   = f2bf(a[i] - bf2f(h0));
        short h1 = f2bf(c[i]); h8[4+i] = h1; l8[4+i] = f2bf(c[i] - bf2f(h1));
    }
}

// ---------------- kernel 1: fused pack + projections ----------------
// y in {0,1}: proj side=y. x encodes (mt 0..7 -> 32-row tile, nh 0..1 -> 128-col half).
// y == 2: pack RT[b][f'][k] (f'=2f: bf16(m*v), f'=2f+1: bf16(m), f'>=72: 0), x*5+r rows.
__global__ void imta_prep(const float* __restrict__ query, const float* __restrict__ key_ts,
                          const float* __restrict__ Wq, const float* __restrict__ Wk,
                          const float* __restrict__ mask, const float* __restrict__ value,
                          char* __restrict__ wsb){
    if (blockIdx.y == 2){
        const int b = blockIdx.z, k = threadIdx.x;
        short* rt = (short*)(wsb + RT_OFF) + b*80*256;
        #pragma unroll
        for (int r = 0; r < 5; ++r){
            const int fp = blockIdx.x*5 + r;
            const int f = fp >> 1;
            short o = 0;
            if (f < NF){
                float m = mask[(b*NTK + k)*NF + f];
                o = (fp & 1) ? f2bf(m) : f2bf(m * value[(b*NTK + k)*NF + f]);
            }
            rt[fp*256 + k] = o;
        }
        return;
    }
    const int side = blockIdx.y, b = blockIdx.z;
    const int mt = blockIdx.x >> 1, nh = blockIdx.x & 1;
    const int t0 = mt*32;
    const int tid = threadIdx.x, w = tid >> 6, lane = tid & 63;
    const int col = lane & 15, quad = lane >> 4;
    const float* __restrict__ X = side ? key_ts : query;
    const float* __restrict__ W = side ? Wk : Wq;
    __shared__ float sX[32][36];
    __shared__ float sW[128][36];
    const int xr = tid >> 3, xc = (tid & 7)*4;     // X staging: 32 rows x 32 d
    const int dr = tid >> 3, dkq = (tid & 7)*4;    // W staging (transpose)
    f32x4 acc[2][2];
    #pragma unroll
    for (int m = 0; m < 2; ++m){ acc[m][0] = (f32x4)0.f; acc[m][1] = (f32x4)0.f; }
    for (int kb = 0; kb < 8; ++kb){
        const int dc = kb*32;
        float4 xv = *(const float4*)(X + (size_t)(b*NTQ + t0 + xr)*ND + dc + xc);
        float4 wv[4];
        #pragma unroll
        for (int jj = 0; jj < 4; ++jj)
            wv[jj] = *(const float4*)(W + (size_t)((4*nh + jj)*ND + dc + dr)*NDK + dkq);
        __syncthreads();                           // previous iter's frag reads done
        *(float4*)&sX[xr][xc] = xv;
        #pragma unroll
        for (int jj = 0; jj < 4; ++jj)
            #pragma unroll
            for (int i = 0; i < 4; ++i)
                sW[jj*32 + dkq + i][dr] = ((const float*)&wv[jj])[i];
        __syncthreads();
        short8 ah[2], al[2], bh[2], bl[2];
        #pragma unroll
        for (int m = 0; m < 2; ++m)
            cvt8(&sX[m*16 + col][quad*8], ah[m], al[m]);
        #pragma unroll
        for (int nt = 0; nt < 2; ++nt)
            cvt8(&sW[(w*2 + nt)*16 + col][quad*8], bh[nt], bl[nt]);
        #pragma unroll
        for (int m = 0; m < 2; ++m)
            #pragma unroll
            for (int nt = 0; nt < 2; ++nt){
                acc[m][nt] = MFMA16(al[m], bh[nt], acc[m][nt]);
                acc[m][nt] = MFMA16(ah[m], bl[nt], acc[m][nt]);
                acc[m][nt] = MFMA16(ah[m], bh[nt], acc[m][nt]);
            }
    }
    short* oh = (short*)(wsb + (side ? KPH_OFF : QPH_OFF));
    short* ol = (short*)(wsb + (side ? KPL_OFF : QPL_OFF));
    #pragma unroll
    for (int m = 0; m < 2; ++m)
        #pragma unroll
        for (int nt = 0; nt < 2; ++nt){
            const int n = (nh*8 + w*2 + nt)*16 + col;
            const int j = n >> 5, dk = n & 31;
            #pragma unroll
            for (int r = 0; r < 4; ++r){
                const int t = t0 + m*16 + quad*4 + r;
                float v = acc[m][nt][r];
                short h = f2bf(v);
                size_t o = (size_t)(((b*NH + j)*NTQ + t)*NDK + dk);
                oh[o] = h; ol[o] = f2bf(v - bf2f(h));
            }
        }
}

// ---------------- kernel 2: attention via MFMA ----------------
// block: (qtile | j | b). phase1: scores (hi/lo 3-pass) -> exp -> E(bf16) in LDS
// phase2: E @ RT^T (interleaved mv/m cols) -> shfl div -> heads
__global__ void imta_attn(char* __restrict__ wsb, const float* __restrict__ value){
    const int t0 = blockIdx.x*64;
    const int j = blockIdx.y, b = blockIdx.z;
    const int tid = threadIdx.x, w = tid >> 6, lane = tid & 63;
    const int col = lane & 15, quad = lane >> 4;
    __shared__ short sE[64*264];               // 33.8 KB; later overlaid by sH
    const short* QH = (const short*)(wsb + QPH_OFF) + (b*NH + j)*NTQ*NDK;
    const short* QL = (const short*)(wsb + QPL_OFF) + (b*NH + j)*NTQ*NDK;
    const short* KH = (const short*)(wsb + KPH_OFF) + (b*NH + j)*NTK*NDK;
    const short* KL = (const short*)(wsb + KPL_OFF) + (b*NH + j)*NTK*NDK;
    const short* RT = (const short*)(wsb + RT_OFF) + b*80*256;
    float* HD = (float*)(wsb + HD_OFF) + (b*NH + j)*NTQ*NF;

    // phase 1: wave w covers keys [64w, 64w+64)
    short8 ah[4], al[4];
    #pragma unroll
    for (int m = 0; m < 4; ++m){
        const int t = t0 + m*16 + col;
        ah[m] = ld8(QH + t*NDK + quad*8);
        al[m] = ld8(QL + t*NDK + quad*8);
    }
    #pragma unroll
    for (int nt = 0; nt < 4; ++nt){
        const int key0 = w*64 + nt*16;
        short8 bh = ld8(KH + (key0 + col)*NDK + quad*8);
        short8 bl = ld8(KL + (key0 + col)*NDK + quad*8);
        f32x4 acc[4];
        #pragma unroll
        for (int m = 0; m < 4; ++m){
            f32x4 c = (f32x4)0.f;
            c = MFMA16(al[m], bh, c);
            c = MFMA16(ah[m], bl, c);
            c = MFMA16(ah[m], bh, c);
            acc[m] = c;
        }
        const int key = key0 + col;
        #pragma unroll
        for (int m = 0; m < 4; ++m)
            #pragma unroll
            for (int r = 0; r < 4; ++r){
                const int q = m*16 + quad*4 + r;
                sE[q*264 + key] = f2bf(__expf(acc[m][r]));
            }
    }
    __syncthreads();

    // phase 2: wave w owns q-range [16w, 16w+16)
    const int q0 = w*16;
    f32x4 acc2[5];
    #pragma unroll
    for (int nt = 0; nt < 5; ++nt) acc2[nt] = (f32x4)0.f;
    #pragma unroll 2
    for (int kb = 0; kb < 8; ++kb){
        const int ko = kb*32 + quad*8;
        short8 a = *(const short8*)&sE[(q0 + col)*264 + ko];
        #pragma unroll
        for (int nt = 0; nt < 5; ++nt){
            short8 bb = ld8(RT + (nt*16 + col)*256 + ko);
            acc2[nt] = MFMA16(a, bb, acc2[nt]);
        }
    }
    __syncthreads();                           // all phase-2 sE reads done
    float* sH = (float*)sE;                    // [64][40] heads staging
    #pragma unroll
    for (int nt = 0; nt < 5; ++nt)
        #pragma unroll
        for (int r = 0; r < 4; ++r){
            float v = acc2[nt][r];
            float o = __shfl_xor(v, 1, 64);
            if (!(col & 1)){
                const int f = nt*8 + (col >> 1);
                if (f < NF){
                    float num = v, den = o, h;
                    if (den != 0.0f) h = num/den;
                    else {
                        float s = 0.f;
                        for (int k = 0; k < NTK; ++k) s += value[(b*NTK + k)*NF + f];
                        h = s * (1.0f/256.0f);
                    }
                    sH[(q0 + quad*4 + r)*40 + f] = h;
                }
            }
        }
    __syncthreads();
    for (int idx = tid; idx < 64*NF; idx += 256){
        const int q = idx/NF, f = idx - q*NF;
        HD[(t0 + q)*NF + f] = sH[q*40 + f];
    }
}

// ---------------- kernel 3: fused head-mix MLP ----------------
__global__ void imta_final(const float* __restrict__ Wc, const float* __restrict__ bc,
                           const float* __restrict__ Wo1, const float* __restrict__ bo1,
                           const float* __restrict__ Wo2, const float* __restrict__ bo2,
                           const float* __restrict__ hd, float* __restrict__ out){
    const int bq = blockIdx.x;
    const int b = bq >> 8, qq = bq & 255;
    const int tid = threadIdx.x;
    __shared__ float sh[NF*NH];
    __shared__ float sW1[NF*NSF];
    for (int t = tid; t < NF*NH; t += 256){
        int jj = t/NF, f = t - jj*NF;
        sh[t] = hd[((b*NH + jj)*NTQ + qq)*NF + f];
    }
    if (tid < NF*NSF) sW1[tid] = Wo1[tid];
    __syncthreads();
    const int d = tid;
    float wcr[8];
    #pragma unroll
    for (int h = 0; h < 8; ++h) wcr[h] = Wc[h*ND + d];
    const float bcd = bc[d];
    float a2[6];
    #pragma unroll
    for (int s = 0; s < 6; ++s) a2[s] = bo1[s];
    #pragma unroll
    for (int f4 = 0; f4 < NF; f4 += 4){
        float4 sv[8];
        #pragma unroll
        for (int h = 0; h < 8; ++h) sv[h] = *(const float4*)&sh[h*NF + f4];
        #pragma unroll
        for (int fi = 0; fi < 4; ++fi){
            float a = bcd;
            #pragma unroll
            for (int h = 0; h < 8; ++h)
                a = fmaf(reinterpret_cast<const float*>(&sv[h])[fi], wcr[h], a);
            float lf = fast_tanh(a);
            const int f = f4 + fi;
            #pragma unroll
            for (int s = 0; s < 6; ++s)
                a2[s] = fmaf(lf, sW1[f*NSF + s], a2[s]);
        }
    }
    float o = bo2[d];
    #pragma unroll
    for (int s = 0; s < 6; ++s)
        o = fmaf(fast_tanh(a2[s]), Wo2[s], o);
    out[(b*NTQ + qq)*ND + d] = o;
}

extern "C" void kernel_launch(void* const* d_in, const int* in_sizes, int n_in,
                              void* d_out, int out_size, void* d_ws, size_t ws_size,
                              hipStream_t stream){
    const float* query  = (const float*)d_in[0];
    const float* key_ts = (const float*)d_in[1];
    const float* value  = (const float*)d_in[2];
    const float* mask   = (const float*)d_in[3];
    const float* Wq     = (const float*)d_in[4];
    const float* Wk     = (const float*)d_in[5];
    const float* Wc     = (const float*)d_in[6];
    const float* bc     = (const float*)d_in[7];
    const float* Wo1    = (const float*)d_in[8];
    const float* bo1    = (const float*)d_in[9];
    const float* Wo2    = (const float*)d_in[10];
    const float* bo2    = (const float*)d_in[11];
    char* wsb  = (char*)d_ws;
    float* out = (float*)d_out;
    (void)in_sizes; (void)n_in; (void)out_size; (void)ws_size;

    imta_prep <<<dim3(16, 3, 16), dim3(256), 0, stream>>>(query, key_ts, Wq, Wk, mask, value, wsb);
    imta_attn <<<dim3(4, 8, 16),  dim3(256), 0, stream>>>(wsb, value);
    imta_final<<<dim3(4096),      dim3(256), 0, stream>>>(Wc, bc, Wo1, bo1, Wo2, bo2,
                                                          (const float*)(wsb + HD_OFF), out);
}